// Round 1
// baseline (582.241 us; speedup 1.0000x reference)
//
#include <hip/hip_runtime.h>
#include <math.h>

// PDELayer: 100 steps of u <- u + alpha(row)*u_xx + beta(col)*u_yy on a
// 50x50 padded grid whose ring is FIXED (reflect pad applied once).
// Layout: one wave per image; lane = padded column (0..49); each lane holds
// its 50-row column in registers. Vertical neighbors in-register, horizontal
// via DPP wave shifts (VALU pipe, no LDS traffic in the hot loop).
// Boundary handled uniformly: pad cells get alpha=beta=0, c0=1 -> new = u.

#define NTSTEPS 100

__device__ __forceinline__ float dpp_nbr_a(float x) {
    // wave_shr:1 — lane i receives lane i-1 (left neighbor); lane 0 -> 0
    return __int_as_float(__builtin_amdgcn_update_dpp(
        0, __float_as_int(x), 0x138, 0xF, 0xF, true));
}
__device__ __forceinline__ float dpp_nbr_b(float x) {
    // wave_shl:1 — lane i receives lane i+1 (right neighbor); lane 63 -> 0
    return __int_as_float(__builtin_amdgcn_update_dpp(
        0, __float_as_int(x), 0x130, 0xF, 0xF, true));
}

__global__ __launch_bounds__(256) void pde_kernel(
    const float* __restrict__ u0,
    const float* __restrict__ pa1, const float* __restrict__ pa2,
    const float* __restrict__ pa3, const float* __restrict__ pb1,
    const float* __restrict__ pb2, const float* __restrict__ pb3,
    float* __restrict__ out)
{
    __shared__ float sh_alpha[48];  // per original row
    __shared__ float sh_beta[48];   // per original col

    const int tid  = threadIdx.x;
    const int lane = tid & 63;
    const int wv   = tid >> 6;
    const int img  = blockIdx.x * 4 + wv;

    if (tid < 48) {
        float a1 = fabsf(pa1[0]), a2 = fabsf(pa2[0]), a3 = fabsf(pa3[0]);
        float b1 = fabsf(pb1[0]), b2 = fabsf(pb2[0]), b3 = fabsf(pb3[0]);
        float t = 6.283185307179586f * ((float)tid / 47.0f);
        float s = sinf(t), c = cosf(t);
        // 0.5*DT/DX^2 = 0.5*1e-4*2304 = 0.1152 ; DT/DY^2 = 0.2304
        sh_alpha[tid] = 0.1152f * (a1 + a2 * s + a3 * c);
        sh_beta[tid]  = 0.2304f * (b1 + b2 * c + b3 * s);
    }
    __syncthreads();

    // lane -> original column of u0 this lane loads (reflect mapping).
    // Pad columns (lane 0, lane 49) and idle lanes (>=50) get m=0 so their
    // state never changes; their loads are clamped to valid addresses.
    const bool incol = (lane >= 1 && lane <= 48);
    const float m = incol ? 1.0f : 0.0f;
    int oc = lane - 1;
    if (lane == 0)  oc = 1;
    if (lane >= 49) oc = 46;

    const float beta = m * sh_beta[oc];

    float u[50];
    float av[49], c0v[49];
    #pragma unroll
    for (int r = 1; r <= 48; ++r) {
        float al = m * sh_alpha[r - 1];
        av[r]  = al;
        c0v[r] = 1.0f - 2.0f * al - 2.0f * beta;
    }

    const float* __restrict__ src = u0 + (size_t)img * 2304;
    #pragma unroll
    for (int r = 0; r < 50; ++r) {
        int orow = (r == 0) ? 1 : ((r <= 48) ? (r - 1) : 46);  // reflect rows
        u[r] = src[orow * 48 + oc];
    }

    #pragma unroll 1
    for (int t = 0; t < NTSTEPS; ++t) {
        float prev = u[0];  // old row r-1 (rolling)
        #pragma unroll
        for (int r = 1; r <= 48; ++r) {
            float hl = dpp_nbr_a(u[r]);
            float hr = dpp_nbr_b(u[r]);
            float h  = hl + hr;          // left + right (symmetric)
            float v  = prev + u[r + 1];  // up + down (old values)
            float nu = u[r] * c0v[r];
            nu = fmaf(av[r], v, nu);
            nu = fmaf(beta, h, nu);
            prev = u[r];
            u[r] = nu;
        }
    }

    if (incol) {
        float* __restrict__ dst = out + (size_t)img * 2304 + oc;
        #pragma unroll
        for (int r = 1; r <= 48; ++r)
            dst[(r - 1) * 48] = u[r];
    }
}

extern "C" void kernel_launch(void* const* d_in, const int* in_sizes, int n_in,
                              void* d_out, int out_size, void* d_ws, size_t ws_size,
                              hipStream_t stream) {
    const float* u0 = (const float*)d_in[0];
    pde_kernel<<<8192 / 4, 256, 0, stream>>>(
        u0,
        (const float*)d_in[1], (const float*)d_in[2], (const float*)d_in[3],
        (const float*)d_in[4], (const float*)d_in[5], (const float*)d_in[6],
        (float*)d_out);
}